// Round 5
// baseline (224.111 us; speedup 1.0000x reference)
//
#include <hip/hip_runtime.h>
#include <math.h>

#define Bc 4
#define Tc 512
#define Fc 512
#define Dc 256
#define RPB 8  // rows per block in projection kernel
#define PF 4   // scan prefetch depth (register circular buffer)

typedef float floatx4 __attribute__((ext_vector_type(4)));

__device__ __forceinline__ float wred(float v) {
#pragma unroll
  for (int off = 32; off; off >>= 1) v += __shfl_xor(v, off, 64);
  return v;
}

// Dual wave64 sum-reduce via DPP (row_shr 1/2/4/8 + row_bcast 15/31).
__device__ __forceinline__ void wred2_dpp(float& a, float& c) {
#define DPP_STEP(ctrl, rmask)                                                 \
  {                                                                           \
    float ta = __int_as_float(__builtin_amdgcn_update_dpp(                    \
        0, __float_as_int(a), (ctrl), (rmask), 0xf, true));                   \
    float tc = __int_as_float(__builtin_amdgcn_update_dpp(                    \
        0, __float_as_int(c), (ctrl), (rmask), 0xf, true));                   \
    a += ta;                                                                  \
    c += tc;                                                                  \
  }
  DPP_STEP(0x111, 0xf)  // row_shr:1
  DPP_STEP(0x112, 0xf)  // row_shr:2
  DPP_STEP(0x114, 0xf)  // row_shr:4
  DPP_STEP(0x118, 0xf)  // row_shr:8
  DPP_STEP(0x142, 0xa)  // row_bcast:15 -> rows 1,3
  DPP_STEP(0x143, 0xc)  // row_bcast:31 -> rows 2,3
#undef DPP_STEP
  a = __int_as_float(__builtin_amdgcn_readlane(__float_as_int(a), 63));
  c = __int_as_float(__builtin_amdgcn_readlane(__float_as_int(c), 63));
}

// ---------------------------------------------------------------------------
// Kernel 1: LayerNorm + K/Q/V/beta/shortcut projections + sum-normalize + kq
// ---------------------------------------------------------------------------
__global__ __launch_bounds__(256) void proj_kernel(
    const float* __restrict__ x, const float* __restrict__ Wk,
    const float* __restrict__ Wq, const float* __restrict__ Wv,
    const float* __restrict__ Wb, const float* __restrict__ gamma,
    const float* __restrict__ beta_ln, const float* __restrict__ Wsc,
    const float* __restrict__ bsc, float* __restrict__ Ko,
    float* __restrict__ Qo, float* __restrict__ Vo, float* __restrict__ ysco,
    float* __restrict__ betao, float* __restrict__ kqo) {
  __shared__ __align__(16) float xn[RPB][Fc];
  __shared__ float red[4][32];
  __shared__ float fin[32];

  const int tid = threadIdx.x;
  const int wave = tid >> 6, lane = tid & 63;
  const int row0 = blockIdx.x * RPB;

#pragma unroll
  for (int rr = 0; rr < 2; ++rr) {
    const int r = wave * 2 + rr;
    const float* xr = x + (size_t)(row0 + r) * Fc;
    float4 a = *(const float4*)&xr[lane * 8];
    float4 b = *(const float4*)&xr[lane * 8 + 4];
    float s8 = a.x + a.y + a.z + a.w + b.x + b.y + b.z + b.w;
    float mu = wred(s8) * (1.0f / Fc);
    float d0 = a.x - mu, d1 = a.y - mu, d2 = a.z - mu, d3 = a.w - mu;
    float d4 = b.x - mu, d5 = b.y - mu, d6 = b.z - mu, d7 = b.w - mu;
    float sq = d0 * d0 + d1 * d1 + d2 * d2 + d3 * d3 + d4 * d4 + d5 * d5 +
               d6 * d6 + d7 * d7;
    float var = wred(sq) * (1.0f / Fc);
    float rs = rsqrtf(var + 1e-5f);
    float4 g0 = *(const float4*)&gamma[lane * 8];
    float4 g1 = *(const float4*)&gamma[lane * 8 + 4];
    float4 bl0 = *(const float4*)&beta_ln[lane * 8];
    float4 bl1 = *(const float4*)&beta_ln[lane * 8 + 4];
    float4 o0 = make_float4(d0 * rs * g0.x + bl0.x, d1 * rs * g0.y + bl0.y,
                            d2 * rs * g0.z + bl0.z, d3 * rs * g0.w + bl0.w);
    float4 o1 = make_float4(d4 * rs * g1.x + bl1.x, d5 * rs * g1.y + bl1.y,
                            d6 * rs * g1.z + bl1.z, d7 * rs * g1.w + bl1.w);
    *(float4*)&xn[r][lane * 8] = o0;
    *(float4*)&xn[r][lane * 8 + 4] = o1;
  }
  __syncthreads();

  const int d = tid;
  float accK[RPB], accQ[RPB], accV[RPB], accS[RPB];
#pragma unroll
  for (int r = 0; r < RPB; ++r) accK[r] = accQ[r] = accV[r] = accS[r] = 0.0f;

  for (int f = 0; f < Fc; f += 4) {
    float wk[4], wq[4], wv[4], ws[4];
#pragma unroll
    for (int ff = 0; ff < 4; ++ff) {
      wk[ff] = Wk[(size_t)(f + ff) * Dc + d];
      wq[ff] = Wq[(size_t)(f + ff) * Dc + d];
      wv[ff] = Wv[(size_t)(f + ff) * Dc + d];
      ws[ff] = Wsc[(size_t)(f + ff) * Dc + d];
    }
#pragma unroll
    for (int r = 0; r < RPB; ++r) {
      float4 xr = *(const float4*)&xn[r][f];
      accK[r] = fmaf(xr.w, wk[3], fmaf(xr.z, wk[2], fmaf(xr.y, wk[1], fmaf(xr.x, wk[0], accK[r]))));
      accQ[r] = fmaf(xr.w, wq[3], fmaf(xr.z, wq[2], fmaf(xr.y, wq[1], fmaf(xr.x, wq[0], accQ[r]))));
      accV[r] = fmaf(xr.w, wv[3], fmaf(xr.z, wv[2], fmaf(xr.y, wv[1], fmaf(xr.x, wv[0], accV[r]))));
      accS[r] = fmaf(xr.w, ws[3], fmaf(xr.z, ws[2], fmaf(xr.y, ws[1], fmaf(xr.x, ws[0], accS[r]))));
    }
  }

  float pk[RPB], pq[RPB];
#pragma unroll
  for (int r = 0; r < RPB; ++r) {
    pk[r] = fmaxf(accK[r], 0.0f);
    pq[r] = fmaxf(accQ[r], 0.0f);
  }
#pragma unroll
  for (int r = 0; r < RPB; ++r) {
    float p0 = wred(pk[r]);
    float p1 = wred(pq[r]);
    float p2 = wred(pk[r] * pq[r]);
    float pb = xn[r][tid] * Wb[tid] + xn[r][tid + 256] * Wb[tid + 256];
    float p3 = wred(pb);
    if (lane == 0) {
      red[wave][r * 4 + 0] = p0;
      red[wave][r * 4 + 1] = p1;
      red[wave][r * 4 + 2] = p2;
      red[wave][r * 4 + 3] = p3;
    }
  }
  __syncthreads();
  if (tid < 32) fin[tid] = red[0][tid] + red[1][tid] + red[2][tid] + red[3][tid];
  __syncthreads();

#pragma unroll
  for (int r = 0; r < RPB; ++r) {
    size_t row = (size_t)(row0 + r);
    float invK = 1.0f / (1e-5f + fin[r * 4 + 0]);
    float invQ = 1.0f / (1e-5f + fin[r * 4 + 1]);
    Ko[row * Dc + d] = pk[r] * invK;
    Qo[row * Dc + d] = pq[r] * invQ;
    Vo[row * Dc + d] = accV[r];
    ysco[row * Dc + d] = accS[r] + bsc[d];
  }
  if (tid < RPB) {
    size_t row = (size_t)(row0 + tid);
    float invK = 1.0f / (1e-5f + fin[tid * 4 + 0]);
    float invQ = 1.0f / (1e-5f + fin[tid * 4 + 1]);
    betao[row] = 1.0f / (1.0f + expf(-fin[tid * 4 + 3]));
    kqo[row] = fin[tid * 4 + 2] * invK * invQ;
  }
}

// ---------------------------------------------------------------------------
// Kernel 2: row-parallel state scan, wave-PAIR per chain (t-parity stores).
// Both waves of a pair redundantly run the recurrence (cheap); each stores
// `states` only for t where (t&1)==half. 2048 waves -> 2 waves/SIMD, so one
// wave's serial chain overlaps the other's store-queue drain. nt stores keep
// the 512 MB stream out of L2 (K/Q/V stay resident).
// ---------------------------------------------------------------------------
__global__ __launch_bounds__(256) void scan_kernel(
    const float* __restrict__ S0, const float* __restrict__ K,
    const float* __restrict__ Q, const float* __restrict__ V,
    const float* __restrict__ ysc, const float* __restrict__ beta,
    const float* __restrict__ kq, float* __restrict__ yout,
    float* __restrict__ states) {
  const int tid = threadIdx.x;
  const int wave = tid >> 6, lane = tid & 63;
  const int flat = blockIdx.x * 4 + wave;  // 0..2047
  const int chain = flat >> 1;             // 0..1023
  const int half = flat & 1;               // t-parity this wave stores
  const int b = chain >> 8;
  const int i = chain & 255;

  float4 s = *(const float4*)&S0[((size_t)(b * Dc + i)) * Dc + lane * 4];

  const float* Kb = K + (size_t)b * Tc * Dc;
  const float* Qb = Q + (size_t)b * Tc * Dc;
  const float* Vb = V + (size_t)b * Tc * Dc;
  const float* Yb = ysc + (size_t)b * Tc * Dc;
  const float* bb_p = beta + (size_t)b * Tc;
  const float* kq_p = kq + (size_t)b * Tc;

  // PF-deep register circular buffers (static indexing only -> stays in VGPRs)
  float4 kb[PF], qb[PF];
  float vb[PF], ybv[PF], bbv[PF], kqb[PF];
#pragma unroll
  for (int j = 0; j < PF; ++j) {
    kb[j] = *(const float4*)&Kb[(size_t)j * Dc + lane * 4];
    qb[j] = *(const float4*)&Qb[(size_t)j * Dc + lane * 4];
    vb[j] = Vb[(size_t)j * Dc + i];
    ybv[j] = Yb[(size_t)j * Dc + i];
    bbv[j] = bb_p[j];
    kqb[j] = kq_p[j];
  }

  for (int t0 = 0; t0 < Tc; t0 += PF) {
#pragma unroll
    for (int j = 0; j < PF; ++j) {
      const int t = t0 + j;
      // consume slot j
      const float4 k = kb[j];
      const float4 q = qb[j];
      const float vv = vb[j];
      const float yb = ybv[j];
      const float bb = bbv[j];
      const float kqv = kqb[j];

      // refill slot j for t+PF (clamped; duplicate last row is harmless)
      const int tn = (t + PF < Tc) ? t + PF : Tc - 1;
      kb[j] = *(const float4*)&Kb[(size_t)tn * Dc + lane * 4];
      qb[j] = *(const float4*)&Qb[(size_t)tn * Dc + lane * 4];
      vb[j] = Vb[(size_t)tn * Dc + i];
      ybv[j] = Yb[(size_t)tn * Dc + i];
      bbv[j] = bb_p[tn];
      kqb[j] = kq_p[tn];

      float a = (s.x * k.x + s.y * k.y) + (s.z * k.z + s.w * k.w);
      float c = (s.x * q.x + s.y * q.y) + (s.z * q.z + s.w * q.w);
      wred2_dpp(a, c);

      const float w = bb * (vv - a);
      s.x = fmaf(w, k.x, s.x);
      s.y = fmaf(w, k.y, s.y);
      s.z = fmaf(w, k.z, s.z);
      s.w = fmaf(w, k.w, s.w);

      if ((t & 1) == half) {
        floatx4 sv;
        sv.x = s.x; sv.y = s.y; sv.z = s.z; sv.w = s.w;
        __builtin_nontemporal_store(
            sv,
            (floatx4*)&states[(((size_t)b * Tc + t) * Dc + i) * Dc + lane * 4]);
        if (lane == 0) yout[((size_t)b * Tc + t) * Dc + i] = c + w * kqv + yb;
      }
    }
  }
}

// ---------------------------------------------------------------------------
extern "C" void kernel_launch(void* const* d_in, const int* in_sizes, int n_in,
                              void* d_out, int out_size, void* d_ws,
                              size_t ws_size, hipStream_t stream) {
  const float* x = (const float*)d_in[0];
  const float* S0 = (const float*)d_in[1];
  const float* Wk = (const float*)d_in[2];
  const float* Wq = (const float*)d_in[3];
  const float* Wv = (const float*)d_in[4];
  const float* Wb = (const float*)d_in[5];
  const float* gamma = (const float*)d_in[6];
  const float* beta_ln = (const float*)d_in[7];
  const float* Wsc = (const float*)d_in[8];
  const float* bsc = (const float*)d_in[9];

  float* out = (float*)d_out;
  float* yout = out;                              // [B,T,D]
  float* states = out + (size_t)Bc * Tc * Dc;     // [B,T,D,D]

  const size_t BTD = (size_t)Bc * Tc * Dc;
  float* ws = (float*)d_ws;
  float* K = ws;
  float* Q = K + BTD;
  float* V = Q + BTD;
  float* ysc = V + BTD;
  float* beta = ysc + BTD;
  float* kq = beta + (size_t)Bc * Tc;

  proj_kernel<<<(Bc * Tc) / RPB, 256, 0, stream>>>(
      x, Wk, Wq, Wv, Wb, gamma, beta_ln, Wsc, bsc, K, Q, V, ysc, beta, kq);
  scan_kernel<<<(Bc * Dc * 2) / 4, 256, 0, stream>>>(S0, K, Q, V, ysc, beta,
                                                     kq, yout, states);
}

// Round 6
// 191.729 us; speedup vs baseline: 1.1689x; 1.1689x over previous
//
#include <hip/hip_runtime.h>
#include <math.h>

#define Bc 4
#define Tc 512
#define Fc 512
#define Dc 256
#define RPB 8  // rows per block in projection kernel
#define PF 4   // scan prefetch depth (register circular buffer)

typedef float floatx4 __attribute__((ext_vector_type(4)));

__device__ __forceinline__ float wred(float v) {
#pragma unroll
  for (int off = 32; off; off >>= 1) v += __shfl_xor(v, off, 64);
  return v;
}

// Dual wave64 sum-reduce via DPP (row_shr 1/2/4/8 + row_bcast 15/31).
__device__ __forceinline__ void wred2_dpp(float& a, float& c) {
#define DPP_STEP(ctrl, rmask)                                                 \
  {                                                                           \
    float ta = __int_as_float(__builtin_amdgcn_update_dpp(                    \
        0, __float_as_int(a), (ctrl), (rmask), 0xf, true));                   \
    float tc = __int_as_float(__builtin_amdgcn_update_dpp(                    \
        0, __float_as_int(c), (ctrl), (rmask), 0xf, true));                   \
    a += ta;                                                                  \
    c += tc;                                                                  \
  }
  DPP_STEP(0x111, 0xf)  // row_shr:1
  DPP_STEP(0x112, 0xf)  // row_shr:2
  DPP_STEP(0x114, 0xf)  // row_shr:4
  DPP_STEP(0x118, 0xf)  // row_shr:8
  DPP_STEP(0x142, 0xa)  // row_bcast:15 -> rows 1,3
  DPP_STEP(0x143, 0xc)  // row_bcast:31 -> rows 2,3
#undef DPP_STEP
  a = __int_as_float(__builtin_amdgcn_readlane(__float_as_int(a), 63));
  c = __int_as_float(__builtin_amdgcn_readlane(__float_as_int(c), 63));
}

// ---------------------------------------------------------------------------
// Kernel 1: LayerNorm + K/Q/V/beta/shortcut projections + sum-normalize + kq
// ---------------------------------------------------------------------------
__global__ __launch_bounds__(256) void proj_kernel(
    const float* __restrict__ x, const float* __restrict__ Wk,
    const float* __restrict__ Wq, const float* __restrict__ Wv,
    const float* __restrict__ Wb, const float* __restrict__ gamma,
    const float* __restrict__ beta_ln, const float* __restrict__ Wsc,
    const float* __restrict__ bsc, float* __restrict__ Ko,
    float* __restrict__ Qo, float* __restrict__ Vo, float* __restrict__ ysco,
    float* __restrict__ betao, float* __restrict__ kqo) {
  __shared__ __align__(16) float xn[RPB][Fc];
  __shared__ float red[4][32];
  __shared__ float fin[32];

  const int tid = threadIdx.x;
  const int wave = tid >> 6, lane = tid & 63;
  const int row0 = blockIdx.x * RPB;

#pragma unroll
  for (int rr = 0; rr < 2; ++rr) {
    const int r = wave * 2 + rr;
    const float* xr = x + (size_t)(row0 + r) * Fc;
    float4 a = *(const float4*)&xr[lane * 8];
    float4 b = *(const float4*)&xr[lane * 8 + 4];
    float s8 = a.x + a.y + a.z + a.w + b.x + b.y + b.z + b.w;
    float mu = wred(s8) * (1.0f / Fc);
    float d0 = a.x - mu, d1 = a.y - mu, d2 = a.z - mu, d3 = a.w - mu;
    float d4 = b.x - mu, d5 = b.y - mu, d6 = b.z - mu, d7 = b.w - mu;
    float sq = d0 * d0 + d1 * d1 + d2 * d2 + d3 * d3 + d4 * d4 + d5 * d5 +
               d6 * d6 + d7 * d7;
    float var = wred(sq) * (1.0f / Fc);
    float rs = rsqrtf(var + 1e-5f);
    float4 g0 = *(const float4*)&gamma[lane * 8];
    float4 g1 = *(const float4*)&gamma[lane * 8 + 4];
    float4 bl0 = *(const float4*)&beta_ln[lane * 8];
    float4 bl1 = *(const float4*)&beta_ln[lane * 8 + 4];
    float4 o0 = make_float4(d0 * rs * g0.x + bl0.x, d1 * rs * g0.y + bl0.y,
                            d2 * rs * g0.z + bl0.z, d3 * rs * g0.w + bl0.w);
    float4 o1 = make_float4(d4 * rs * g1.x + bl1.x, d5 * rs * g1.y + bl1.y,
                            d6 * rs * g1.z + bl1.z, d7 * rs * g1.w + bl1.w);
    *(float4*)&xn[r][lane * 8] = o0;
    *(float4*)&xn[r][lane * 8 + 4] = o1;
  }
  __syncthreads();

  const int d = tid;
  float accK[RPB], accQ[RPB], accV[RPB], accS[RPB];
#pragma unroll
  for (int r = 0; r < RPB; ++r) accK[r] = accQ[r] = accV[r] = accS[r] = 0.0f;

  for (int f = 0; f < Fc; f += 4) {
    float wk[4], wq[4], wv[4], ws[4];
#pragma unroll
    for (int ff = 0; ff < 4; ++ff) {
      wk[ff] = Wk[(size_t)(f + ff) * Dc + d];
      wq[ff] = Wq[(size_t)(f + ff) * Dc + d];
      wv[ff] = Wv[(size_t)(f + ff) * Dc + d];
      ws[ff] = Wsc[(size_t)(f + ff) * Dc + d];
    }
#pragma unroll
    for (int r = 0; r < RPB; ++r) {
      float4 xr = *(const float4*)&xn[r][f];
      accK[r] = fmaf(xr.w, wk[3], fmaf(xr.z, wk[2], fmaf(xr.y, wk[1], fmaf(xr.x, wk[0], accK[r]))));
      accQ[r] = fmaf(xr.w, wq[3], fmaf(xr.z, wq[2], fmaf(xr.y, wq[1], fmaf(xr.x, wq[0], accQ[r]))));
      accV[r] = fmaf(xr.w, wv[3], fmaf(xr.z, wv[2], fmaf(xr.y, wv[1], fmaf(xr.x, wv[0], accV[r]))));
      accS[r] = fmaf(xr.w, ws[3], fmaf(xr.z, ws[2], fmaf(xr.y, ws[1], fmaf(xr.x, ws[0], accS[r]))));
    }
  }

  float pk[RPB], pq[RPB];
#pragma unroll
  for (int r = 0; r < RPB; ++r) {
    pk[r] = fmaxf(accK[r], 0.0f);
    pq[r] = fmaxf(accQ[r], 0.0f);
  }
#pragma unroll
  for (int r = 0; r < RPB; ++r) {
    float p0 = wred(pk[r]);
    float p1 = wred(pq[r]);
    float p2 = wred(pk[r] * pq[r]);
    float pb = xn[r][tid] * Wb[tid] + xn[r][tid + 256] * Wb[tid + 256];
    float p3 = wred(pb);
    if (lane == 0) {
      red[wave][r * 4 + 0] = p0;
      red[wave][r * 4 + 1] = p1;
      red[wave][r * 4 + 2] = p2;
      red[wave][r * 4 + 3] = p3;
    }
  }
  __syncthreads();
  if (tid < 32) fin[tid] = red[0][tid] + red[1][tid] + red[2][tid] + red[3][tid];
  __syncthreads();

#pragma unroll
  for (int r = 0; r < RPB; ++r) {
    size_t row = (size_t)(row0 + r);
    float invK = 1.0f / (1e-5f + fin[r * 4 + 0]);
    float invQ = 1.0f / (1e-5f + fin[r * 4 + 1]);
    Ko[row * Dc + d] = pk[r] * invK;
    Qo[row * Dc + d] = pq[r] * invQ;
    Vo[row * Dc + d] = accV[r];
    ysco[row * Dc + d] = accS[r] + bsc[d];
  }
  if (tid < RPB) {
    size_t row = (size_t)(row0 + tid);
    float invK = 1.0f / (1e-5f + fin[tid * 4 + 0]);
    float invQ = 1.0f / (1e-5f + fin[tid * 4 + 1]);
    betao[row] = 1.0f / (1.0f + expf(-fin[tid * 4 + 3]));
    kqo[row] = fin[tid * 4 + 2] * invK * invQ;
  }
}

// ---------------------------------------------------------------------------
// Kernel 2: row-parallel state scan, one wave per (b,i) chain (R4 structure)
// + XCD-locality swizzle: blocks round-robin to XCDs as (bid & 7), so map
// batch b = (bid&7)>>1 -> each XCD reads only ONE batch's K/Q/V/ysc (2 MB),
// which fits its private 4 MB L2. Without this, every XCD touches all 4
// batches (8 MB > 4 MB) and prefetches miss to HBM (R1/R2: FETCH 33 MB vs
// 8 MB compulsory). nt stores keep the 512 MB states stream out of L2.
// ---------------------------------------------------------------------------
__global__ __launch_bounds__(256) void scan_kernel(
    const float* __restrict__ S0, const float* __restrict__ K,
    const float* __restrict__ Q, const float* __restrict__ V,
    const float* __restrict__ ysc, const float* __restrict__ beta,
    const float* __restrict__ kq, float* __restrict__ yout,
    float* __restrict__ states) {
  const int tid = threadIdx.x;
  const int wave = tid >> 6, lane = tid & 63;
  const int bid = blockIdx.x;            // 0..255
  const int xcd = bid & 7;               // dispatch round-robin XCD id
  const int slot = bid >> 3;             // 0..31
  const int b = xcd >> 1;                // 2 XCDs per batch
  const int jgrp = ((xcd & 1) << 5) | slot;  // 0..63 within batch
  const int i = jgrp * 4 + wave;         // 0..255 state row

  float4 s = *(const float4*)&S0[((size_t)(b * Dc + i)) * Dc + lane * 4];

  const float* Kb = K + (size_t)b * Tc * Dc;
  const float* Qb = Q + (size_t)b * Tc * Dc;
  const float* Vb = V + (size_t)b * Tc * Dc;
  const float* Yb = ysc + (size_t)b * Tc * Dc;
  const float* bb_p = beta + (size_t)b * Tc;
  const float* kq_p = kq + (size_t)b * Tc;

  // PF-deep register circular buffers (static indexing only -> stays in VGPRs)
  float4 kb[PF], qb[PF];
  float vb[PF], ybv[PF], bbv[PF], kqb[PF];
#pragma unroll
  for (int j = 0; j < PF; ++j) {
    kb[j] = *(const float4*)&Kb[(size_t)j * Dc + lane * 4];
    qb[j] = *(const float4*)&Qb[(size_t)j * Dc + lane * 4];
    vb[j] = Vb[(size_t)j * Dc + i];
    ybv[j] = Yb[(size_t)j * Dc + i];
    bbv[j] = bb_p[j];
    kqb[j] = kq_p[j];
  }

  for (int t0 = 0; t0 < Tc; t0 += PF) {
#pragma unroll
    for (int j = 0; j < PF; ++j) {
      const int t = t0 + j;
      // consume slot j
      const float4 k = kb[j];
      const float4 q = qb[j];
      const float vv = vb[j];
      const float yb = ybv[j];
      const float bb = bbv[j];
      const float kqv = kqb[j];

      // refill slot j for t+PF (clamped; duplicate last row is harmless)
      const int tn = (t + PF < Tc) ? t + PF : Tc - 1;
      kb[j] = *(const float4*)&Kb[(size_t)tn * Dc + lane * 4];
      qb[j] = *(const float4*)&Qb[(size_t)tn * Dc + lane * 4];
      vb[j] = Vb[(size_t)tn * Dc + i];
      ybv[j] = Yb[(size_t)tn * Dc + i];
      bbv[j] = bb_p[tn];
      kqb[j] = kq_p[tn];

      float a = (s.x * k.x + s.y * k.y) + (s.z * k.z + s.w * k.w);
      float c = (s.x * q.x + s.y * q.y) + (s.z * q.z + s.w * q.w);
      wred2_dpp(a, c);

      const float w = bb * (vv - a);
      s.x = fmaf(w, k.x, s.x);
      s.y = fmaf(w, k.y, s.y);
      s.z = fmaf(w, k.z, s.z);
      s.w = fmaf(w, k.w, s.w);

      floatx4 sv;
      sv.x = s.x; sv.y = s.y; sv.z = s.z; sv.w = s.w;
      __builtin_nontemporal_store(
          sv,
          (floatx4*)&states[(((size_t)b * Tc + t) * Dc + i) * Dc + lane * 4]);
      if (lane == 0) yout[((size_t)b * Tc + t) * Dc + i] = c + w * kqv + yb;
    }
  }
}

// ---------------------------------------------------------------------------
extern "C" void kernel_launch(void* const* d_in, const int* in_sizes, int n_in,
                              void* d_out, int out_size, void* d_ws,
                              size_t ws_size, hipStream_t stream) {
  const float* x = (const float*)d_in[0];
  const float* S0 = (const float*)d_in[1];
  const float* Wk = (const float*)d_in[2];
  const float* Wq = (const float*)d_in[3];
  const float* Wv = (const float*)d_in[4];
  const float* Wb = (const float*)d_in[5];
  const float* gamma = (const float*)d_in[6];
  const float* beta_ln = (const float*)d_in[7];
  const float* Wsc = (const float*)d_in[8];
  const float* bsc = (const float*)d_in[9];

  float* out = (float*)d_out;
  float* yout = out;                              // [B,T,D]
  float* states = out + (size_t)Bc * Tc * Dc;     // [B,T,D,D]

  const size_t BTD = (size_t)Bc * Tc * Dc;
  float* ws = (float*)d_ws;
  float* K = ws;
  float* Q = K + BTD;
  float* V = Q + BTD;
  float* ysc = V + BTD;
  float* beta = ysc + BTD;
  float* kq = beta + (size_t)Bc * Tc;

  proj_kernel<<<(Bc * Tc) / RPB, 256, 0, stream>>>(
      x, Wk, Wq, Wv, Wb, gamma, beta_ln, Wsc, bsc, K, Q, V, ysc, beta, kq);
  scan_kernel<<<(Bc * Dc) / 4, 256, 0, stream>>>(S0, K, Q, V, ysc, beta, kq,
                                                 yout, states);
}